// Round 2
// baseline (1003.416 us; speedup 1.0000x reference)
//
#include <hip/hip_runtime.h>

#define NFEAT 128
#define NGRAPH 64

// ---------------- index dtype handling ----------------
// Reference uses int64 indices; harness doc says integer -> const int*.
// Sniff at runtime: for int64 data, every odd dword (high word) is 0.

__device__ __forceinline__ int load_idx(const void* p, long long i, int is64) {
    return is64 ? (int)((const long long*)p)[i] : ((const int*)p)[i];
}

__global__ void detect_kernel(const unsigned int* __restrict__ ei_raw, int* __restrict__ flag) {
    __shared__ int any32;
    if (threadIdx.x == 0) any32 = 0;
    __syncthreads();
    for (int i = threadIdx.x; i < 1024; i += 256) {
        if (ei_raw[2 * i + 1] != 0u) any32 = 1;  // benign race
    }
    __syncthreads();
    if (threadIdx.x == 0) *flag = any32 ? 0 : 1;  // 1 => int64
}

// ---------------- CSR build ----------------

__global__ void deg_kernel(const void* __restrict__ ei, const int* __restrict__ flag,
                           int* __restrict__ cnt, int nE) {
    int is64 = *flag;
    int e = blockIdx.x * blockDim.x + threadIdx.x;
    if (e < nE) atomicAdd(&cnt[load_idx(ei, (long long)nE + e, is64)], 1);
}

// exclusive scan over cnt[n] -> row_start (chunk-local), bsum[b] = chunk total.
// Also emits dinv[i] = rsqrt(deg_i + 1) (self-loop included).
__global__ void scanA(const int* __restrict__ cnt, int* __restrict__ row_start,
                      int* __restrict__ bsum, float* __restrict__ dinv, int n) {
    __shared__ int buf[256];
    int i = blockIdx.x * 256 + threadIdx.x;
    int v = (i < n) ? cnt[i] : 0;
    if (i < n) dinv[i] = rsqrtf((float)v + 1.0f);
    buf[threadIdx.x] = v;
    __syncthreads();
    int x = v;
    for (int off = 1; off < 256; off <<= 1) {
        int t = (threadIdx.x >= (unsigned)off) ? buf[threadIdx.x - off] : 0;
        __syncthreads();
        x += t;
        buf[threadIdx.x] = x;
        __syncthreads();
    }
    if (i < n) row_start[i] = x - v;               // chunk-local exclusive
    if (threadIdx.x == 255) bsum[blockIdx.x] = x;  // chunk total
}

// single block: exclusive scan of bsum[nb] in place; grand total -> *total
__global__ void scanB(int* __restrict__ bsum, int nb, int* __restrict__ total) {
    __shared__ int buf[256];
    int v = (threadIdx.x < (unsigned)nb) ? bsum[threadIdx.x] : 0;
    buf[threadIdx.x] = v;
    __syncthreads();
    int x = v;
    for (int off = 1; off < 256; off <<= 1) {
        int t = (threadIdx.x >= (unsigned)off) ? buf[threadIdx.x - off] : 0;
        __syncthreads();
        x += t;
        buf[threadIdx.x] = x;
        __syncthreads();
    }
    if (threadIdx.x < (unsigned)nb) bsum[threadIdx.x] = x - v;
    if (threadIdx.x == 255) *total = buf[255];
}

__global__ void scanC(int* __restrict__ row_start, const int* __restrict__ bsum, int n) {
    int i = blockIdx.x * 256 + threadIdx.x;
    if (i < n) row_start[i] += bsum[blockIdx.x];
}

__global__ void fill_kernel(const void* __restrict__ ei, const int* __restrict__ flag,
                            const int* __restrict__ row_start, int* __restrict__ cursor,
                            const float* __restrict__ dinv, int* __restrict__ csr_src,
                            float* __restrict__ csr_norm, int nE) {
    int is64 = *flag;
    int e = blockIdx.x * blockDim.x + threadIdx.x;
    if (e >= nE) return;
    int u = load_idx(ei, e, is64);
    int v = load_idx(ei, (long long)nE + e, is64);
    int pos = row_start[v] + atomicAdd(&cursor[v], 1);
    csr_src[pos]  = u;
    csr_norm[pos] = dinv[u] * dinv[v];
}

// ---------------- GEMM: out[n,128] = in[n,128] @ W[128,128] ----------------

__global__ __launch_bounds__(256) void gemm_kernel(const float* __restrict__ in,
                                                   const float* __restrict__ W,
                                                   float* __restrict__ out, int n) {
    __shared__ float xs[8][128];
    int r0 = blockIdx.x * 8;
    for (int i = threadIdx.x; i < 8 * 128; i += 256) {
        int r = i >> 7, c = i & 127;
        xs[r][c] = (r0 + r < n) ? in[(size_t)(r0 + r) * NFEAT + c] : 0.0f;
    }
    __syncthreads();
    int c  = threadIdx.x & 127;
    int rh = threadIdx.x >> 7;  // 0 or 1 -> rows rh*4 .. rh*4+3
    float a0 = 0.f, a1 = 0.f, a2 = 0.f, a3 = 0.f;
#pragma unroll 4
    for (int k = 0; k < 128; k++) {
        float w = W[k * NFEAT + c];
        a0 += xs[rh * 4 + 0][k] * w;
        a1 += xs[rh * 4 + 1][k] * w;
        a2 += xs[rh * 4 + 2][k] * w;
        a3 += xs[rh * 4 + 3][k] * w;
    }
    int rb = r0 + rh * 4;
    if (rb + 0 < n) out[(size_t)(rb + 0) * NFEAT + c] = a0;
    if (rb + 1 < n) out[(size_t)(rb + 1) * NFEAT + c] = a1;
    if (rb + 2 < n) out[(size_t)(rb + 2) * NFEAT + c] = a2;
    if (rb + 3 < n) out[(size_t)(rb + 3) * NFEAT + c] = a3;
}

// ---------------- aggregation ----------------
// out[v] = sum_{e in row v} h[src_e]*norm_e + h[v]*dinv[v]^2 + b ; optional relu.
// One 64-lane wave per node; lane carries a float2 (features 2*lane, 2*lane+1).
// Unroll-4 keeps 4 x 512B row gathers in flight (L2/LLC latency hiding).

__global__ __launch_bounds__(256) void agg_kernel(const float* __restrict__ h,
                                                  const int* __restrict__ row_start,
                                                  const int* __restrict__ csr_src,
                                                  const float* __restrict__ csr_norm,
                                                  const float* __restrict__ dinv,
                                                  const float* __restrict__ bias,
                                                  float* __restrict__ out, int n, int do_relu) {
    int v = blockIdx.x * 4 + (threadIdx.x >> 6);
    if (v >= n) return;
    int lane = threadIdx.x & 63;
    float ax = 0.f, ay = 0.f;
    int s = row_start[v], e = row_start[v + 1];
    int i = s;
    for (; i + 3 < e; i += 4) {
        int u0 = csr_src[i + 0], u1 = csr_src[i + 1];
        int u2 = csr_src[i + 2], u3 = csr_src[i + 3];
        float n0 = csr_norm[i + 0], n1 = csr_norm[i + 1];
        float n2 = csr_norm[i + 2], n3 = csr_norm[i + 3];
        float2 h0 = *reinterpret_cast<const float2*>(h + (size_t)u0 * NFEAT + lane * 2);
        float2 h1 = *reinterpret_cast<const float2*>(h + (size_t)u1 * NFEAT + lane * 2);
        float2 h2 = *reinterpret_cast<const float2*>(h + (size_t)u2 * NFEAT + lane * 2);
        float2 h3 = *reinterpret_cast<const float2*>(h + (size_t)u3 * NFEAT + lane * 2);
        ax += n0 * h0.x + n1 * h1.x + n2 * h2.x + n3 * h3.x;
        ay += n0 * h0.y + n1 * h1.y + n2 * h2.y + n3 * h3.y;
    }
    for (; i < e; i++) {
        int u0 = csr_src[i];
        float n0 = csr_norm[i];
        float2 h0 = *reinterpret_cast<const float2*>(h + (size_t)u0 * NFEAT + lane * 2);
        ax += n0 * h0.x;
        ay += n0 * h0.y;
    }
    float dv = dinv[v];
    float nm = dv * dv;
    float2 hv = *reinterpret_cast<const float2*>(h + (size_t)v * NFEAT + lane * 2);
    ax += nm * hv.x + bias[lane * 2 + 0];
    ay += nm * hv.y + bias[lane * 2 + 1];
    if (do_relu) {
        ax = fmaxf(ax, 0.f);
        ay = fmaxf(ay, 0.f);
    }
    float2 o;
    o.x = ax;
    o.y = ay;
    *reinterpret_cast<float2*>(out + (size_t)v * NFEAT + lane * 2) = o;
}

// ---------------- pooling ----------------

__global__ void bounds_kernel(const void* __restrict__ batch, const int* __restrict__ flag,
                              int* __restrict__ gstart, int* __restrict__ gend, int n) {
    int is64 = *flag;
    int i = blockIdx.x * blockDim.x + threadIdx.x;
    if (i < n) {
        int g = load_idx(batch, i, is64);
        atomicMin(&gstart[g], i);
        atomicMax(&gend[g], i + 1);
    }
}

__global__ void pool_kernel(const float* __restrict__ B, const int* __restrict__ gstart,
                            const int* __restrict__ gend, float* __restrict__ pooled) {
    int g = blockIdx.x;
    int c = threadIdx.x;  // 128 threads
    int s = gstart[g], e = gend[g];
    float acc = 0.f;
    for (int i = s; i < e; i++) acc += B[(size_t)i * NFEAT + c];
    int cn = e - s;
    float denom = (cn > 0) ? (float)cn : 1.0f;
    pooled[g * NFEAT + c] = acc / denom;
}

__global__ void final_kernel(const float* __restrict__ pooled, const float* __restrict__ lw,
                             const float* __restrict__ lb, float* __restrict__ out) {
    int idx = blockIdx.x * blockDim.x + threadIdx.x;
    if (idx >= NGRAPH * 16) return;
    int g = idx >> 4, c = idx & 15;
    float acc = lb[c];
#pragma unroll 8
    for (int k = 0; k < 128; k++) acc += pooled[g * NFEAT + k] * lw[k * 16 + c];
    out[idx] = acc;
}

// ---------------- launch ----------------

extern "C" void kernel_launch(void* const* d_in, const int* in_sizes, int n_in,
                              void* d_out, int out_size, void* d_ws, size_t ws_size,
                              hipStream_t stream) {
    const float* x   = (const float*)d_in[0];
    const void*  ei  = d_in[1];
    const void*  bat = d_in[2];
    const float* W1  = (const float*)d_in[3];
    const float* b1  = (const float*)d_in[4];
    const float* W2  = (const float*)d_in[5];
    const float* b2  = (const float*)d_in[6];
    const float* W3  = (const float*)d_in[7];
    const float* b3  = (const float*)d_in[8];
    const float* lw  = (const float*)d_in[9];
    const float* lb  = (const float*)d_in[10];
    float*       out = (float*)d_out;

    const int n  = in_sizes[0] / NFEAT;  // 50000
    const int nE = in_sizes[1] / 2;      // 800000

    // workspace layout (256B aligned)
    char* ws = (char*)d_ws;
    size_t off = 0;
    auto alloc = [&](size_t bytes) -> char* {
        char* p = ws + off;
        off = (off + bytes + 255) & ~(size_t)255;
        return p;
    };
    int*   flag      = (int*)alloc(256);
    int*   cnt       = (int*)alloc((size_t)n * 4);
    int*   row_start = (int*)alloc((size_t)(n + 1) * 4);
    int*   cursor    = (int*)alloc((size_t)n * 4);
    int*   bsum      = (int*)alloc(1024);
    int*   csr_src   = (int*)alloc((size_t)nE * 4);
    float* csr_norm  = (float*)alloc((size_t)nE * 4);
    float* dinv      = (float*)alloc((size_t)n * 4);
    int*   gstart    = (int*)alloc(NGRAPH * 4);
    int*   gend      = (int*)alloc(NGRAPH * 4);
    float* pooled    = (float*)alloc(NGRAPH * NFEAT * 4);
    float* bufA      = (float*)alloc((size_t)n * NFEAT * 4);
    float* bufB      = (float*)alloc((size_t)n * NFEAT * 4);
    (void)ws_size;

    const int TB  = 256;
    const int nbE = (nE + TB - 1) / TB;
    const int nbN = (n + TB - 1) / TB;

    // zero / init
    hipMemsetAsync(cnt, 0, (size_t)n * 4, stream);
    hipMemsetAsync(cursor, 0, (size_t)n * 4, stream);
    hipMemsetAsync(gstart, 0x7f, NGRAPH * 4, stream);
    hipMemsetAsync(gend, 0, NGRAPH * 4, stream);

    // dtype sniff (int32 vs int64 indices)
    detect_kernel<<<1, 256, 0, stream>>>((const unsigned int*)ei, flag);

    // degree
    deg_kernel<<<nbE, TB, 0, stream>>>(ei, flag, cnt, nE);

    // exclusive scan -> row_start ; also dinv
    scanA<<<nbN, 256, 0, stream>>>(cnt, row_start, bsum, dinv, n);
    scanB<<<1, 256, 0, stream>>>(bsum, nbN, row_start + n);
    scanC<<<nbN, 256, 0, stream>>>(row_start, bsum, n);

    // CSR fill
    fill_kernel<<<nbE, TB, 0, stream>>>(ei, flag, row_start, cursor, dinv,
                                        csr_src, csr_norm, nE);

    const int gemmBlocks = (n + 7) / 8;
    const int aggBlocks  = (n + 3) / 4;

    // layer 1: h = x@W1 -> A ; agg(A) -> B (relu)
    gemm_kernel<<<gemmBlocks, 256, 0, stream>>>(x, W1, bufA, n);
    agg_kernel<<<aggBlocks, 256, 0, stream>>>(bufA, row_start, csr_src, csr_norm,
                                              dinv, b1, bufB, n, 1);
    // layer 2
    gemm_kernel<<<gemmBlocks, 256, 0, stream>>>(bufB, W2, bufA, n);
    agg_kernel<<<aggBlocks, 256, 0, stream>>>(bufA, row_start, csr_src, csr_norm,
                                              dinv, b2, bufB, n, 1);
    // layer 3 (no relu)
    gemm_kernel<<<gemmBlocks, 256, 0, stream>>>(bufB, W3, bufA, n);
    agg_kernel<<<aggBlocks, 256, 0, stream>>>(bufA, row_start, csr_src, csr_norm,
                                              dinv, b3, bufB, n, 0);

    // pooling
    bounds_kernel<<<nbN, TB, 0, stream>>>(bat, flag, gstart, gend, n);
    pool_kernel<<<NGRAPH, NFEAT, 0, stream>>>(bufB, gstart, gend, pooled);

    // final linear: 64x16
    final_kernel<<<(NGRAPH * 16 + 255) / 256, 256, 0, stream>>>(pooled, lw, lb, out);
}

// Round 3
// 522.227 us; speedup vs baseline: 1.9214x; 1.9214x over previous
//
#include <hip/hip_runtime.h>

#define NFEAT 128
#define NGRAPH 64
#define POOL_SPLIT 8

// ---------------- index dtype handling ----------------
// Reference uses int64 indices; harness doc says integer -> const int*.
// Sniff at runtime: for int64 data, every odd dword (high word) is 0.

__device__ __forceinline__ int load_idx(const void* p, long long i, int is64) {
    return is64 ? (int)((const long long*)p)[i] : ((const int*)p)[i];
}

__global__ void detect_kernel(const unsigned int* __restrict__ ei_raw, int* __restrict__ flag) {
    __shared__ int any32;
    if (threadIdx.x == 0) any32 = 0;
    __syncthreads();
    for (int i = threadIdx.x; i < 1024; i += 256) {
        if (ei_raw[2 * i + 1] != 0u) any32 = 1;  // benign race
    }
    __syncthreads();
    if (threadIdx.x == 0) *flag = any32 ? 0 : 1;  // 1 => int64
}

// ---------------- CSR build ----------------

__global__ void deg_kernel(const void* __restrict__ ei, const int* __restrict__ flag,
                           int* __restrict__ cnt, int nE) {
    int is64 = *flag;
    int e = blockIdx.x * blockDim.x + threadIdx.x;
    if (e < nE) atomicAdd(&cnt[load_idx(ei, (long long)nE + e, is64)], 1);
}

// exclusive scan over cnt[n] -> row_start (chunk-local), bsum[b] = chunk total.
// Also emits dinv[i] = rsqrt(deg_i + 1) (self-loop included).
__global__ void scanA(const int* __restrict__ cnt, int* __restrict__ row_start,
                      int* __restrict__ bsum, float* __restrict__ dinv, int n) {
    __shared__ int buf[256];
    int i = blockIdx.x * 256 + threadIdx.x;
    int v = (i < n) ? cnt[i] : 0;
    if (i < n) dinv[i] = rsqrtf((float)v + 1.0f);
    buf[threadIdx.x] = v;
    __syncthreads();
    int x = v;
    for (int off = 1; off < 256; off <<= 1) {
        int t = (threadIdx.x >= (unsigned)off) ? buf[threadIdx.x - off] : 0;
        __syncthreads();
        x += t;
        buf[threadIdx.x] = x;
        __syncthreads();
    }
    if (i < n) row_start[i] = x - v;               // chunk-local exclusive
    if (threadIdx.x == 255) bsum[blockIdx.x] = x;  // chunk total
}

// single block: exclusive scan of bsum[nb] in place; grand total -> *total
__global__ void scanB(int* __restrict__ bsum, int nb, int* __restrict__ total) {
    __shared__ int buf[256];
    int v = (threadIdx.x < (unsigned)nb) ? bsum[threadIdx.x] : 0;
    buf[threadIdx.x] = v;
    __syncthreads();
    int x = v;
    for (int off = 1; off < 256; off <<= 1) {
        int t = (threadIdx.x >= (unsigned)off) ? buf[threadIdx.x - off] : 0;
        __syncthreads();
        x += t;
        buf[threadIdx.x] = x;
        __syncthreads();
    }
    if (threadIdx.x < (unsigned)nb) bsum[threadIdx.x] = x - v;
    if (threadIdx.x == 255) *total = buf[255];
}

__global__ void scanC(int* __restrict__ row_start, const int* __restrict__ bsum, int n) {
    int i = blockIdx.x * 256 + threadIdx.x;
    if (i < n) row_start[i] += bsum[blockIdx.x];
}

__global__ void fill_kernel(const void* __restrict__ ei, const int* __restrict__ flag,
                            const int* __restrict__ row_start, int* __restrict__ cursor,
                            const float* __restrict__ dinv, int* __restrict__ csr_src,
                            float* __restrict__ csr_norm, int nE) {
    int is64 = *flag;
    int e = blockIdx.x * blockDim.x + threadIdx.x;
    if (e >= nE) return;
    int u = load_idx(ei, e, is64);
    int v = load_idx(ei, (long long)nE + e, is64);
    int pos = row_start[v] + atomicAdd(&cursor[v], 1);
    csr_src[pos]  = u;
    csr_norm[pos] = dinv[u] * dinv[v];
}

// ---------------- GEMM: out[n,128] = in[n,128] @ W[128,128] ----------------

__global__ __launch_bounds__(256) void gemm_kernel(const float* __restrict__ in,
                                                   const float* __restrict__ W,
                                                   float* __restrict__ out, int n) {
    __shared__ float xs[8][128];
    int r0 = blockIdx.x * 8;
    for (int i = threadIdx.x; i < 8 * 128; i += 256) {
        int r = i >> 7, c = i & 127;
        xs[r][c] = (r0 + r < n) ? in[(size_t)(r0 + r) * NFEAT + c] : 0.0f;
    }
    __syncthreads();
    int c  = threadIdx.x & 127;
    int rh = threadIdx.x >> 7;  // 0 or 1 -> rows rh*4 .. rh*4+3
    float a0 = 0.f, a1 = 0.f, a2 = 0.f, a3 = 0.f;
#pragma unroll 4
    for (int k = 0; k < 128; k++) {
        float w = W[k * NFEAT + c];
        a0 += xs[rh * 4 + 0][k] * w;
        a1 += xs[rh * 4 + 1][k] * w;
        a2 += xs[rh * 4 + 2][k] * w;
        a3 += xs[rh * 4 + 3][k] * w;
    }
    int rb = r0 + rh * 4;
    if (rb + 0 < n) out[(size_t)(rb + 0) * NFEAT + c] = a0;
    if (rb + 1 < n) out[(size_t)(rb + 1) * NFEAT + c] = a1;
    if (rb + 2 < n) out[(size_t)(rb + 2) * NFEAT + c] = a2;
    if (rb + 3 < n) out[(size_t)(rb + 3) * NFEAT + c] = a3;
}

// ---------------- aggregation ----------------
// out[v] = sum_{e in row v} h[src_e]*norm_e + h[v]*dinv[v]^2 + b ; optional relu.
// One 64-lane wave per node; lane carries a float2 (features 2*lane, 2*lane+1).
// Unroll-4 keeps 4 x 512B row gathers in flight (L2/LLC latency hiding).

__global__ __launch_bounds__(256) void agg_kernel(const float* __restrict__ h,
                                                  const int* __restrict__ row_start,
                                                  const int* __restrict__ csr_src,
                                                  const float* __restrict__ csr_norm,
                                                  const float* __restrict__ dinv,
                                                  const float* __restrict__ bias,
                                                  float* __restrict__ out, int n, int do_relu) {
    int v = blockIdx.x * 4 + (threadIdx.x >> 6);
    if (v >= n) return;
    int lane = threadIdx.x & 63;
    float ax = 0.f, ay = 0.f;
    int s = row_start[v], e = row_start[v + 1];
    int i = s;
    for (; i + 3 < e; i += 4) {
        int u0 = csr_src[i + 0], u1 = csr_src[i + 1];
        int u2 = csr_src[i + 2], u3 = csr_src[i + 3];
        float n0 = csr_norm[i + 0], n1 = csr_norm[i + 1];
        float n2 = csr_norm[i + 2], n3 = csr_norm[i + 3];
        float2 h0 = *reinterpret_cast<const float2*>(h + (size_t)u0 * NFEAT + lane * 2);
        float2 h1 = *reinterpret_cast<const float2*>(h + (size_t)u1 * NFEAT + lane * 2);
        float2 h2 = *reinterpret_cast<const float2*>(h + (size_t)u2 * NFEAT + lane * 2);
        float2 h3 = *reinterpret_cast<const float2*>(h + (size_t)u3 * NFEAT + lane * 2);
        ax += n0 * h0.x + n1 * h1.x + n2 * h2.x + n3 * h3.x;
        ay += n0 * h0.y + n1 * h1.y + n2 * h2.y + n3 * h3.y;
    }
    for (; i < e; i++) {
        int u0 = csr_src[i];
        float n0 = csr_norm[i];
        float2 h0 = *reinterpret_cast<const float2*>(h + (size_t)u0 * NFEAT + lane * 2);
        ax += n0 * h0.x;
        ay += n0 * h0.y;
    }
    float dv = dinv[v];
    float nm = dv * dv;
    float2 hv = *reinterpret_cast<const float2*>(h + (size_t)v * NFEAT + lane * 2);
    ax += nm * hv.x + bias[lane * 2 + 0];
    ay += nm * hv.y + bias[lane * 2 + 1];
    if (do_relu) {
        ax = fmaxf(ax, 0.f);
        ay = fmaxf(ay, 0.f);
    }
    float2 o;
    o.x = ax;
    o.y = ay;
    *reinterpret_cast<float2*>(out + (size_t)v * NFEAT + lane * 2) = o;
}

// ---------------- pooling ----------------
// batch is SORTED (reference sorts it) -> segment bounds by boundary detection.
// No atomics: the round-2 atomicMin/Max version burned 295us on 64 contended
// addresses (WRITE_SIZE 3.1MB of cache-line ping-pong).

__global__ void bounds_kernel(const void* __restrict__ batch, const int* __restrict__ flag,
                              int* __restrict__ gstart, int* __restrict__ gend, int n) {
    int is64 = *flag;
    int i = blockIdx.x * blockDim.x + threadIdx.x;
    if (i >= n) return;
    int g = load_idx(batch, i, is64);
    if (i == 0) {
        gstart[g] = 0;
    } else {
        int gp = load_idx(batch, i - 1, is64);
        if (gp != g) {
            gend[gp]  = i;
            gstart[g] = i;
        }
    }
    if (i == n - 1) gend[g] = n;
}

// phase 1: each (graph, part) block sums its chunk of rows -> psum
__global__ void pool_kernel(const float* __restrict__ B, const int* __restrict__ gstart,
                            const int* __restrict__ gend, float* __restrict__ psum) {
    int g    = blockIdx.x / POOL_SPLIT;
    int part = blockIdx.x % POOL_SPLIT;
    int c    = threadIdx.x;  // 128 threads
    int s = gstart[g], e = gend[g];
    if (s > e) { s = 0; e = 0; }  // empty graph (gstart stays 0x7f7f7f7f)
    int len   = e - s;
    int chunk = (len + POOL_SPLIT - 1) / POOL_SPLIT;
    int ls = s + part * chunk;
    int le = min(ls + chunk, e);
    float acc = 0.f;
    for (int i = ls; i < le; i++) acc += B[(size_t)i * NFEAT + c];
    psum[((size_t)g * POOL_SPLIT + part) * NFEAT + c] = acc;
}

// phase 2: reduce parts, divide by count
__global__ void pool_reduce_kernel(const float* __restrict__ psum, const int* __restrict__ gstart,
                                   const int* __restrict__ gend, float* __restrict__ pooled) {
    int g = blockIdx.x;
    int c = threadIdx.x;
    float acc = 0.f;
#pragma unroll
    for (int p = 0; p < POOL_SPLIT; p++)
        acc += psum[((size_t)g * POOL_SPLIT + p) * NFEAT + c];
    int cn = gend[g] - gstart[g];
    float denom = (cn > 0) ? (float)cn : 1.0f;
    pooled[g * NFEAT + c] = acc / denom;
}

__global__ void final_kernel(const float* __restrict__ pooled, const float* __restrict__ lw,
                             const float* __restrict__ lb, float* __restrict__ out) {
    int idx = blockIdx.x * blockDim.x + threadIdx.x;
    if (idx >= NGRAPH * 16) return;
    int g = idx >> 4, c = idx & 15;
    float acc = lb[c];
#pragma unroll 8
    for (int k = 0; k < 128; k++) acc += pooled[g * NFEAT + k] * lw[k * 16 + c];
    out[idx] = acc;
}

// ---------------- launch ----------------

extern "C" void kernel_launch(void* const* d_in, const int* in_sizes, int n_in,
                              void* d_out, int out_size, void* d_ws, size_t ws_size,
                              hipStream_t stream) {
    const float* x   = (const float*)d_in[0];
    const void*  ei  = d_in[1];
    const void*  bat = d_in[2];
    const float* W1  = (const float*)d_in[3];
    const float* b1  = (const float*)d_in[4];
    const float* W2  = (const float*)d_in[5];
    const float* b2  = (const float*)d_in[6];
    const float* W3  = (const float*)d_in[7];
    const float* b3  = (const float*)d_in[8];
    const float* lw  = (const float*)d_in[9];
    const float* lb  = (const float*)d_in[10];
    float*       out = (float*)d_out;

    const int n  = in_sizes[0] / NFEAT;  // 50000
    const int nE = in_sizes[1] / 2;      // 800000

    // workspace layout (256B aligned)
    char* ws = (char*)d_ws;
    size_t off = 0;
    auto alloc = [&](size_t bytes) -> char* {
        char* p = ws + off;
        off = (off + bytes + 255) & ~(size_t)255;
        return p;
    };
    int*   flag      = (int*)alloc(256);
    int*   cnt       = (int*)alloc((size_t)n * 4);
    int*   row_start = (int*)alloc((size_t)(n + 1) * 4);
    int*   cursor    = (int*)alloc((size_t)n * 4);
    int*   bsum      = (int*)alloc(1024);
    int*   csr_src   = (int*)alloc((size_t)nE * 4);
    float* csr_norm  = (float*)alloc((size_t)nE * 4);
    float* dinv      = (float*)alloc((size_t)n * 4);
    int*   gstart    = (int*)alloc(NGRAPH * 4);
    int*   gend      = (int*)alloc(NGRAPH * 4);
    float* psum      = (float*)alloc((size_t)NGRAPH * POOL_SPLIT * NFEAT * 4);
    float* pooled    = (float*)alloc(NGRAPH * NFEAT * 4);
    float* bufA      = (float*)alloc((size_t)n * NFEAT * 4);
    float* bufB      = (float*)alloc((size_t)n * NFEAT * 4);
    (void)ws_size;

    const int TB  = 256;
    const int nbE = (nE + TB - 1) / TB;
    const int nbN = (n + TB - 1) / TB;

    // zero / init
    hipMemsetAsync(cnt, 0, (size_t)n * 4, stream);
    hipMemsetAsync(cursor, 0, (size_t)n * 4, stream);
    hipMemsetAsync(gstart, 0x7f, NGRAPH * 4, stream);
    hipMemsetAsync(gend, 0, NGRAPH * 4, stream);

    // dtype sniff (int32 vs int64 indices)
    detect_kernel<<<1, 256, 0, stream>>>((const unsigned int*)ei, flag);

    // degree
    deg_kernel<<<nbE, TB, 0, stream>>>(ei, flag, cnt, nE);

    // exclusive scan -> row_start ; also dinv
    scanA<<<nbN, 256, 0, stream>>>(cnt, row_start, bsum, dinv, n);
    scanB<<<1, 256, 0, stream>>>(bsum, nbN, row_start + n);
    scanC<<<nbN, 256, 0, stream>>>(row_start, bsum, n);

    // CSR fill
    fill_kernel<<<nbE, TB, 0, stream>>>(ei, flag, row_start, cursor, dinv,
                                        csr_src, csr_norm, nE);

    const int gemmBlocks = (n + 7) / 8;
    const int aggBlocks  = (n + 3) / 4;

    // layer 1: h = x@W1 -> A ; agg(A) -> B (relu)
    gemm_kernel<<<gemmBlocks, 256, 0, stream>>>(x, W1, bufA, n);
    agg_kernel<<<aggBlocks, 256, 0, stream>>>(bufA, row_start, csr_src, csr_norm,
                                              dinv, b1, bufB, n, 1);
    // layer 2
    gemm_kernel<<<gemmBlocks, 256, 0, stream>>>(bufB, W2, bufA, n);
    agg_kernel<<<aggBlocks, 256, 0, stream>>>(bufA, row_start, csr_src, csr_norm,
                                              dinv, b2, bufB, n, 1);
    // layer 3 (no relu)
    gemm_kernel<<<gemmBlocks, 256, 0, stream>>>(bufB, W3, bufA, n);
    agg_kernel<<<aggBlocks, 256, 0, stream>>>(bufA, row_start, csr_src, csr_norm,
                                              dinv, b3, bufB, n, 0);

    // pooling: boundary detect (no atomics) + two-phase mean
    bounds_kernel<<<nbN, TB, 0, stream>>>(bat, flag, gstart, gend, n);
    pool_kernel<<<NGRAPH * POOL_SPLIT, NFEAT, 0, stream>>>(bufB, gstart, gend, psum);
    pool_reduce_kernel<<<NGRAPH, NFEAT, 0, stream>>>(psum, gstart, gend, pooled);

    // final linear: 64x16
    final_kernel<<<(NGRAPH * 16 + 255) / 256, 256, 0, stream>>>(pooled, lw, lb, out);
}

// Round 10
// 517.891 us; speedup vs baseline: 1.9375x; 1.0084x over previous
//
#include <hip/hip_runtime.h>

#define NFEAT 128
#define NGRAPH 64
#define POOL_SPLIT 8
#define GR 32  // gemm rows per block

// ---------------- index dtype handling ----------------

__device__ __forceinline__ int load_idx(const void* p, long long i, int is64) {
    return is64 ? (int)((const long long*)p)[i] : ((const int*)p)[i];
}

__global__ void detect_kernel(const unsigned int* __restrict__ ei_raw, int* __restrict__ flag) {
    __shared__ int any32;
    if (threadIdx.x == 0) any32 = 0;
    __syncthreads();
    for (int i = threadIdx.x; i < 1024; i += 256) {
        if (ei_raw[2 * i + 1] != 0u) any32 = 1;  // benign race
    }
    __syncthreads();
    if (threadIdx.x == 0) *flag = any32 ? 0 : 1;  // 1 => int64
}

// ---------------- CSR build ----------------

__global__ void deg_kernel(const void* __restrict__ ei, const int* __restrict__ flag,
                           int* __restrict__ cnt, int nE) {
    int is64 = *flag;
    int e = blockIdx.x * blockDim.x + threadIdx.x;
    if (e < nE) atomicAdd(&cnt[load_idx(ei, (long long)nE + e, is64)], 1);
}

__global__ void scanA(const int* __restrict__ cnt, int* __restrict__ row_start,
                      int* __restrict__ bsum, float* __restrict__ dinv, int n) {
    __shared__ int buf[256];
    int i = blockIdx.x * 256 + threadIdx.x;
    int v = (i < n) ? cnt[i] : 0;
    if (i < n) dinv[i] = rsqrtf((float)v + 1.0f);
    buf[threadIdx.x] = v;
    __syncthreads();
    int x = v;
    for (int off = 1; off < 256; off <<= 1) {
        int t = (threadIdx.x >= (unsigned)off) ? buf[threadIdx.x - off] : 0;
        __syncthreads();
        x += t;
        buf[threadIdx.x] = x;
        __syncthreads();
    }
    if (i < n) row_start[i] = x - v;
    if (threadIdx.x == 255) bsum[blockIdx.x] = x;
}

__global__ void scanB(int* __restrict__ bsum, int nb, int* __restrict__ total) {
    __shared__ int buf[256];
    int v = (threadIdx.x < (unsigned)nb) ? bsum[threadIdx.x] : 0;
    buf[threadIdx.x] = v;
    __syncthreads();
    int x = v;
    for (int off = 1; off < 256; off <<= 1) {
        int t = (threadIdx.x >= (unsigned)off) ? buf[threadIdx.x - off] : 0;
        __syncthreads();
        x += t;
        buf[threadIdx.x] = x;
        __syncthreads();
    }
    if (threadIdx.x < (unsigned)nb) bsum[threadIdx.x] = x - v;
    if (threadIdx.x == 255) *total = buf[255];
}

__global__ void scanC(int* __restrict__ row_start, const int* __restrict__ bsum, int n) {
    int i = blockIdx.x * 256 + threadIdx.x;
    if (i < n) row_start[i] += bsum[blockIdx.x];
}

__global__ void fill_kernel(const void* __restrict__ ei, const int* __restrict__ flag,
                            const int* __restrict__ row_start, int* __restrict__ cursor,
                            const float* __restrict__ dinv, int* __restrict__ csr_src,
                            float* __restrict__ csr_norm, int nE) {
    int is64 = *flag;
    int e = blockIdx.x * blockDim.x + threadIdx.x;
    if (e >= nE) return;
    int u = load_idx(ei, e, is64);
    int v = load_idx(ei, (long long)nE + e, is64);
    int pos = row_start[v] + atomicAdd(&cursor[v], 1);
    csr_src[pos]  = u;
    csr_norm[pos] = dinv[u] * dinv[v];
}

// ---------------- GEMM: out[n,128] = in[n,128] @ W[128,128] ----------------
// W fully staged in LDS (64KB) + 32-row x tile (16KB) -> 80KB, 2 blocks/CU
// (gfx950 allows up to 160KB/workgroup). 4x4 register tile per thread:
// per k = 1 ds_read_b128 (W, conflict-free) + 4 ds_read_b32 (x, 2-way
// broadcast = free) + 16 FMA.

__global__ __launch_bounds__(256) void gemm_kernel(const float* __restrict__ in,
                                                   const float* __restrict__ W,
                                                   float* __restrict__ out, int n) {
    __shared__ float Wl[128 * 128];
    __shared__ float xs[GR][128];
    const int t  = threadIdx.x;
    const int r0 = blockIdx.x * GR;

    // stage W: 4096 float4
    for (int i = t; i < 128 * 128 / 4; i += 256)
        ((float4*)Wl)[i] = ((const float4*)W)[i];
    // stage x tile: 1024 float4
    for (int i = t; i < GR * 128 / 4; i += 256) {
        int r  = i >> 5;
        int c4 = i & 31;
        float4 v = make_float4(0.f, 0.f, 0.f, 0.f);
        if (r0 + r < n) v = ((const float4*)(in + (size_t)(r0 + r) * NFEAT))[c4];
        ((float4*)&xs[r][0])[c4] = v;
    }
    __syncthreads();

    const int c4 = (t & 31) * 4;
    const int r4 = (t >> 5) * 4;
    float4 acc0 = make_float4(0.f, 0.f, 0.f, 0.f);
    float4 acc1 = acc0, acc2 = acc0, acc3 = acc0;

#pragma unroll 8
    for (int k = 0; k < 128; k++) {
        float4 wv = *(const float4*)&Wl[k * 128 + c4];
        float x0 = xs[r4 + 0][k];
        float x1 = xs[r4 + 1][k];
        float x2 = xs[r4 + 2][k];
        float x3 = xs[r4 + 3][k];
        acc0.x += x0 * wv.x; acc0.y += x0 * wv.y; acc0.z += x0 * wv.z; acc0.w += x0 * wv.w;
        acc1.x += x1 * wv.x; acc1.y += x1 * wv.y; acc1.z += x1 * wv.z; acc1.w += x1 * wv.w;
        acc2.x += x2 * wv.x; acc2.y += x2 * wv.y; acc2.z += x2 * wv.z; acc2.w += x2 * wv.w;
        acc3.x += x3 * wv.x; acc3.y += x3 * wv.y; acc3.z += x3 * wv.z; acc3.w += x3 * wv.w;
    }

    float4 a[4] = {acc0, acc1, acc2, acc3};
#pragma unroll
    for (int i = 0; i < 4; i++) {
        int r = r0 + r4 + i;
        if (r < n) *(float4*)&out[(size_t)r * NFEAT + c4] = a[i];
    }
}

// ---------------- aggregation ----------------
// out[v] = sum_{e in row v} h[src_e]*norm_e + h[v]*dinv[v]^2 + b ; optional relu.
// 32-lane half-wave per node, lane holds float4 (32 x 16B = one 512B row per
// instruction). Unroll-4: 2 nodes/wave x 4 rows in flight = 4KB/wave.

__global__ __launch_bounds__(256) void agg_kernel(const float* __restrict__ h,
                                                  const int* __restrict__ row_start,
                                                  const int* __restrict__ csr_src,
                                                  const float* __restrict__ csr_norm,
                                                  const float* __restrict__ dinv,
                                                  const float* __restrict__ bias,
                                                  float* __restrict__ out, int n, int do_relu) {
    int v = blockIdx.x * 8 + (threadIdx.x >> 5);
    if (v >= n) return;
    int lane = threadIdx.x & 31;
    int fo   = lane * 4;
    float4 acc = make_float4(0.f, 0.f, 0.f, 0.f);
    int s = row_start[v], e = row_start[v + 1];
    int i = s;
    for (; i + 3 < e; i += 4) {
        int u0 = csr_src[i + 0], u1 = csr_src[i + 1];
        int u2 = csr_src[i + 2], u3 = csr_src[i + 3];
        float n0 = csr_norm[i + 0], n1 = csr_norm[i + 1];
        float n2 = csr_norm[i + 2], n3 = csr_norm[i + 3];
        float4 h0 = *(const float4*)(h + (size_t)u0 * NFEAT + fo);
        float4 h1 = *(const float4*)(h + (size_t)u1 * NFEAT + fo);
        float4 h2 = *(const float4*)(h + (size_t)u2 * NFEAT + fo);
        float4 h3 = *(const float4*)(h + (size_t)u3 * NFEAT + fo);
        acc.x += n0 * h0.x + n1 * h1.x + n2 * h2.x + n3 * h3.x;
        acc.y += n0 * h0.y + n1 * h1.y + n2 * h2.y + n3 * h3.y;
        acc.z += n0 * h0.z + n1 * h1.z + n2 * h2.z + n3 * h3.z;
        acc.w += n0 * h0.w + n1 * h1.w + n2 * h2.w + n3 * h3.w;
    }
    for (; i < e; i++) {
        int u0 = csr_src[i];
        float n0 = csr_norm[i];
        float4 h0 = *(const float4*)(h + (size_t)u0 * NFEAT + fo);
        acc.x += n0 * h0.x;
        acc.y += n0 * h0.y;
        acc.z += n0 * h0.z;
        acc.w += n0 * h0.w;
    }
    float dv = dinv[v];
    float nm = dv * dv;
    float4 hv = *(const float4*)(h + (size_t)v * NFEAT + fo);
    float4 bv = *(const float4*)(bias + fo);
    acc.x += nm * hv.x + bv.x;
    acc.y += nm * hv.y + bv.y;
    acc.z += nm * hv.z + bv.z;
    acc.w += nm * hv.w + bv.w;
    if (do_relu) {
        acc.x = fmaxf(acc.x, 0.f);
        acc.y = fmaxf(acc.y, 0.f);
        acc.z = fmaxf(acc.z, 0.f);
        acc.w = fmaxf(acc.w, 0.f);
    }
    *(float4*)(out + (size_t)v * NFEAT + fo) = acc;
}

// ---------------- pooling (batch sorted -> boundary detect, no atomics) ----------------

__global__ void bounds_kernel(const void* __restrict__ batch, const int* __restrict__ flag,
                              int* __restrict__ gstart, int* __restrict__ gend, int n) {
    int is64 = *flag;
    int i = blockIdx.x * blockDim.x + threadIdx.x;
    if (i >= n) return;
    int g = load_idx(batch, i, is64);
    if (i == 0) {
        gstart[g] = 0;
    } else {
        int gp = load_idx(batch, i - 1, is64);
        if (gp != g) {
            gend[gp]  = i;
            gstart[g] = i;
        }
    }
    if (i == n - 1) gend[g] = n;
}

__global__ void pool_kernel(const float* __restrict__ B, const int* __restrict__ gstart,
                            const int* __restrict__ gend, float* __restrict__ psum) {
    int g    = blockIdx.x / POOL_SPLIT;
    int part = blockIdx.x % POOL_SPLIT;
    int c    = threadIdx.x;
    int s = gstart[g], e = gend[g];
    if (s > e) { s = 0; e = 0; }
    int len   = e - s;
    int chunk = (len + POOL_SPLIT - 1) / POOL_SPLIT;
    int ls = s + part * chunk;
    int le = min(ls + chunk, e);
    float acc = 0.f;
    for (int i = ls; i < le; i++) acc += B[(size_t)i * NFEAT + c];
    psum[((size_t)g * POOL_SPLIT + part) * NFEAT + c] = acc;
}

__global__ void pool_reduce_kernel(const float* __restrict__ psum, const int* __restrict__ gstart,
                                   const int* __restrict__ gend, float* __restrict__ pooled) {
    int g = blockIdx.x;
    int c = threadIdx.x;
    float acc = 0.f;
#pragma unroll
    for (int p = 0; p < POOL_SPLIT; p++)
        acc += psum[((size_t)g * POOL_SPLIT + p) * NFEAT + c];
    int cn = gend[g] - gstart[g];
    float denom = (cn > 0) ? (float)cn : 1.0f;
    pooled[g * NFEAT + c] = acc / denom;
}

__global__ void final_kernel(const float* __restrict__ pooled, const float* __restrict__ lw,
                             const float* __restrict__ lb, float* __restrict__ out) {
    int idx = blockIdx.x * blockDim.x + threadIdx.x;
    if (idx >= NGRAPH * 16) return;
    int g = idx >> 4, c = idx & 15;
    float acc = lb[c];
#pragma unroll 8
    for (int k = 0; k < 128; k++) acc += pooled[g * NFEAT + k] * lw[k * 16 + c];
    out[idx] = acc;
}

// ---------------- launch ----------------

extern "C" void kernel_launch(void* const* d_in, const int* in_sizes, int n_in,
                              void* d_out, int out_size, void* d_ws, size_t ws_size,
                              hipStream_t stream) {
    const float* x   = (const float*)d_in[0];
    const void*  ei  = d_in[1];
    const void*  bat = d_in[2];
    const float* W1  = (const float*)d_in[3];
    const float* b1  = (const float*)d_in[4];
    const float* W2  = (const float*)d_in[5];
    const float* b2  = (const float*)d_in[6];
    const float* W3  = (const float*)d_in[7];
    const float* b3  = (const float*)d_in[8];
    const float* lw  = (const float*)d_in[9];
    const float* lb  = (const float*)d_in[10];
    float*       out = (float*)d_out;

    const int n  = in_sizes[0] / NFEAT;  // 50000
    const int nE = in_sizes[1] / 2;      // 800000

    char* ws = (char*)d_ws;
    size_t off = 0;
    auto alloc = [&](size_t bytes) -> char* {
        char* p = ws + off;
        off = (off + bytes + 255) & ~(size_t)255;
        return p;
    };
    int*   flag      = (int*)alloc(256);
    int*   cnt       = (int*)alloc((size_t)n * 4);
    int*   row_start = (int*)alloc((size_t)(n + 1) * 4);
    int*   cursor    = (int*)alloc((size_t)n * 4);
    int*   bsum      = (int*)alloc(1024);
    int*   csr_src   = (int*)alloc((size_t)nE * 4);
    float* csr_norm  = (float*)alloc((size_t)nE * 4);
    float* dinv      = (float*)alloc((size_t)n * 4);
    int*   gstart    = (int*)alloc(NGRAPH * 4);
    int*   gend      = (int*)alloc(NGRAPH * 4);
    float* psum      = (float*)alloc((size_t)NGRAPH * POOL_SPLIT * NFEAT * 4);
    float* pooled    = (float*)alloc(NGRAPH * NFEAT * 4);
    float* bufA      = (float*)alloc((size_t)n * NFEAT * 4);
    float* bufB      = (float*)alloc((size_t)n * NFEAT * 4);
    (void)ws_size;

    const int TB  = 256;
    const int nbE = (nE + TB - 1) / TB;
    const int nbN = (n + TB - 1) / TB;

    hipMemsetAsync(cnt, 0, (size_t)n * 4, stream);
    hipMemsetAsync(cursor, 0, (size_t)n * 4, stream);
    hipMemsetAsync(gstart, 0x7f, NGRAPH * 4, stream);
    hipMemsetAsync(gend, 0, NGRAPH * 4, stream);

    detect_kernel<<<1, 256, 0, stream>>>((const unsigned int*)ei, flag);
    deg_kernel<<<nbE, TB, 0, stream>>>(ei, flag, cnt, nE);
    scanA<<<nbN, 256, 0, stream>>>(cnt, row_start, bsum, dinv, n);
    scanB<<<1, 256, 0, stream>>>(bsum, nbN, row_start + n);
    scanC<<<nbN, 256, 0, stream>>>(row_start, bsum, n);
    fill_kernel<<<nbE, TB, 0, stream>>>(ei, flag, row_start, cursor, dinv,
                                        csr_src, csr_norm, nE);

    const int gemmBlocks = (n + GR - 1) / GR;
    const int aggBlocks  = (n + 7) / 8;

    gemm_kernel<<<gemmBlocks, 256, 0, stream>>>(x, W1, bufA, n);
    agg_kernel<<<aggBlocks, 256, 0, stream>>>(bufA, row_start, csr_src, csr_norm,
                                              dinv, b1, bufB, n, 1);
    gemm_kernel<<<gemmBlocks, 256, 0, stream>>>(bufB, W2, bufA, n);
    agg_kernel<<<aggBlocks, 256, 0, stream>>>(bufA, row_start, csr_src, csr_norm,
                                              dinv, b2, bufB, n, 1);
    gemm_kernel<<<gemmBlocks, 256, 0, stream>>>(bufB, W3, bufA, n);
    agg_kernel<<<aggBlocks, 256, 0, stream>>>(bufA, row_start, csr_src, csr_norm,
                                              dinv, b3, bufB, n, 0);

    bounds_kernel<<<nbN, TB, 0, stream>>>(bat, flag, gstart, gend, n);
    pool_kernel<<<NGRAPH * POOL_SPLIT, NFEAT, 0, stream>>>(bufB, gstart, gend, psum);
    pool_reduce_kernel<<<NGRAPH, NFEAT, 0, stream>>>(psum, gstart, gend, pooled);
    final_kernel<<<(NGRAPH * 16 + 255) / 256, 256, 0, stream>>>(pooled, lw, lb, out);
}

// Round 12
// 497.412 us; speedup vs baseline: 2.0173x; 1.0412x over previous
//
#include <hip/hip_runtime.h>

#define NFEAT 128
#define NGRAPH 64
#define POOL_SPLIT 8
#define GR 32  // gemm rows per block

// ---------------- index dtype handling ----------------

__device__ __forceinline__ int load_idx(const void* p, long long i, int is64) {
    return is64 ? (int)((const long long*)p)[i] : ((const int*)p)[i];
}

__global__ void detect_kernel(const unsigned int* __restrict__ ei_raw, int* __restrict__ flag) {
    __shared__ int any32;
    if (threadIdx.x == 0) any32 = 0;
    __syncthreads();
    for (int i = threadIdx.x; i < 1024; i += 256) {
        if (ei_raw[2 * i + 1] != 0u) any32 = 1;  // benign race
    }
    __syncthreads();
    if (threadIdx.x == 0) *flag = any32 ? 0 : 1;  // 1 => int64
}

// ---------------- CSR build ----------------

__global__ void deg_kernel(const void* __restrict__ ei, const int* __restrict__ flag,
                           int* __restrict__ cnt, int nE) {
    int is64 = *flag;
    int e = blockIdx.x * blockDim.x + threadIdx.x;
    if (e < nE) atomicAdd(&cnt[load_idx(ei, (long long)nE + e, is64)], 1);
}

__global__ void scanA(const int* __restrict__ cnt, int* __restrict__ row_start,
                      int* __restrict__ bsum, float* __restrict__ dinv, int n) {
    __shared__ int buf[256];
    int i = blockIdx.x * 256 + threadIdx.x;
    int v = (i < n) ? cnt[i] : 0;
    if (i < n) dinv[i] = rsqrtf((float)v + 1.0f);
    buf[threadIdx.x] = v;
    __syncthreads();
    int x = v;
    for (int off = 1; off < 256; off <<= 1) {
        int t = (threadIdx.x >= (unsigned)off) ? buf[threadIdx.x - off] : 0;
        __syncthreads();
        x += t;
        buf[threadIdx.x] = x;
        __syncthreads();
    }
    if (i < n) row_start[i] = x - v;
    if (threadIdx.x == 255) bsum[blockIdx.x] = x;
}

__global__ void scanB(int* __restrict__ bsum, int nb, int* __restrict__ total) {
    __shared__ int buf[256];
    int v = (threadIdx.x < (unsigned)nb) ? bsum[threadIdx.x] : 0;
    buf[threadIdx.x] = v;
    __syncthreads();
    int x = v;
    for (int off = 1; off < 256; off <<= 1) {
        int t = (threadIdx.x >= (unsigned)off) ? buf[threadIdx.x - off] : 0;
        __syncthreads();
        x += t;
        buf[threadIdx.x] = x;
        __syncthreads();
    }
    if (threadIdx.x < (unsigned)nb) bsum[threadIdx.x] = x - v;
    if (threadIdx.x == 255) *total = buf[255];
}

__global__ void scanC(int* __restrict__ row_start, const int* __restrict__ bsum, int n) {
    int i = blockIdx.x * 256 + threadIdx.x;
    if (i < n) row_start[i] += bsum[blockIdx.x];
}

// CSR entry packed: .x = src index (bitcast int), .y = norm. One 8B scattered
// write instead of two distant 4B writes -> half the touched cache lines.
__global__ void fill_kernel(const void* __restrict__ ei, const int* __restrict__ flag,
                            const int* __restrict__ row_start, int* __restrict__ cursor,
                            const float* __restrict__ dinv, float2* __restrict__ csr, int nE) {
    int is64 = *flag;
    int e = blockIdx.x * blockDim.x + threadIdx.x;
    if (e >= nE) return;
    int u = load_idx(ei, e, is64);
    int v = load_idx(ei, (long long)nE + e, is64);
    int pos = row_start[v] + atomicAdd(&cursor[v], 1);
    float2 c;
    c.x = __int_as_float(u);
    c.y = dinv[u] * dinv[v];
    csr[pos] = c;
}

// ---------------- GEMM: out[n,128] = in[n,128] @ W[128,128] ----------------
// v2 (round 10): stage ONLY the x tile in LDS (16KB -> 8 blocks/CU, 32 waves);
// read W straight from global per-k as float4 (W is 64KB, L2-resident, the
// same rows are broadcast to all blocks). Round-4's 80KB W+x staging capped
// occupancy at 2 blocks/CU and exposed staging latency -> no gain over round 2.

__global__ __launch_bounds__(256) void gemm_kernel(const float* __restrict__ in,
                                                   const float* __restrict__ W,
                                                   float* __restrict__ out, int n) {
    __shared__ float xs[GR][128];
    const int t  = threadIdx.x;
    const int r0 = blockIdx.x * GR;

    // stage x tile: 1024 float4
    for (int i = t; i < GR * 128 / 4; i += 256) {
        int r  = i >> 5;
        int c4 = i & 31;
        float4 v = make_float4(0.f, 0.f, 0.f, 0.f);
        if (r0 + r < n) v = ((const float4*)(in + (size_t)(r0 + r) * NFEAT))[c4];
        ((float4*)&xs[r][0])[c4] = v;
    }
    __syncthreads();

    const int c4idx = t & 31;        // float4 column index
    const int r4    = (t >> 5) * 4;  // 4 rows per thread
    const float4* W4 = (const float4*)W;  // W[k][c] -> W4[k*32 + c4idx]

    float4 acc0 = make_float4(0.f, 0.f, 0.f, 0.f);
    float4 acc1 = acc0, acc2 = acc0, acc3 = acc0;

#pragma unroll 8
    for (int k = 0; k < 128; k++) {
        float4 wv = W4[k * 32 + c4idx];
        float x0 = xs[r4 + 0][k];
        float x1 = xs[r4 + 1][k];
        float x2 = xs[r4 + 2][k];
        float x3 = xs[r4 + 3][k];
        acc0.x += x0 * wv.x; acc0.y += x0 * wv.y; acc0.z += x0 * wv.z; acc0.w += x0 * wv.w;
        acc1.x += x1 * wv.x; acc1.y += x1 * wv.y; acc1.z += x1 * wv.z; acc1.w += x1 * wv.w;
        acc2.x += x2 * wv.x; acc2.y += x2 * wv.y; acc2.z += x2 * wv.z; acc2.w += x2 * wv.w;
        acc3.x += x3 * wv.x; acc3.y += x3 * wv.y; acc3.z += x3 * wv.z; acc3.w += x3 * wv.w;
    }

    float4 a[4] = {acc0, acc1, acc2, acc3};
#pragma unroll
    for (int i = 0; i < 4; i++) {
        int r = r0 + r4 + i;
        if (r < n) ((float4*)&out[(size_t)r * NFEAT])[c4idx] = a[i];
    }
}

// ---------------- aggregation ----------------
// At the gather-fabric ceiling (r10: FETCH flat 189MB, time flat, unroll 2->4
// gave only -5%). Unchanged this round except packed csr stream.

__global__ __launch_bounds__(256) void agg_kernel(const float* __restrict__ h,
                                                  const int* __restrict__ row_start,
                                                  const float2* __restrict__ csr,
                                                  const float* __restrict__ dinv,
                                                  const float* __restrict__ bias,
                                                  float* __restrict__ out, int n, int do_relu) {
    int v = blockIdx.x * 8 + (threadIdx.x >> 5);
    if (v >= n) return;
    int lane = threadIdx.x & 31;
    int fo   = lane * 4;
    float4 acc = make_float4(0.f, 0.f, 0.f, 0.f);
    int s = row_start[v], e = row_start[v + 1];
    int i = s;
    for (; i + 3 < e; i += 4) {
        float2 c0 = csr[i + 0], c1 = csr[i + 1], c2 = csr[i + 2], c3 = csr[i + 3];
        int u0 = __float_as_int(c0.x), u1 = __float_as_int(c1.x);
        int u2 = __float_as_int(c2.x), u3 = __float_as_int(c3.x);
        float4 h0 = *(const float4*)(h + (size_t)u0 * NFEAT + fo);
        float4 h1 = *(const float4*)(h + (size_t)u1 * NFEAT + fo);
        float4 h2 = *(const float4*)(h + (size_t)u2 * NFEAT + fo);
        float4 h3 = *(const float4*)(h + (size_t)u3 * NFEAT + fo);
        acc.x += c0.y * h0.x + c1.y * h1.x + c2.y * h2.x + c3.y * h3.x;
        acc.y += c0.y * h0.y + c1.y * h1.y + c2.y * h2.y + c3.y * h3.y;
        acc.z += c0.y * h0.z + c1.y * h1.z + c2.y * h2.z + c3.y * h3.z;
        acc.w += c0.y * h0.w + c1.y * h1.w + c2.y * h2.w + c3.y * h3.w;
    }
    for (; i < e; i++) {
        float2 c0 = csr[i];
        int u0 = __float_as_int(c0.x);
        float4 h0 = *(const float4*)(h + (size_t)u0 * NFEAT + fo);
        acc.x += c0.y * h0.x;
        acc.y += c0.y * h0.y;
        acc.z += c0.y * h0.z;
        acc.w += c0.y * h0.w;
    }
    float dv = dinv[v];
    float nm = dv * dv;
    float4 hv = *(const float4*)(h + (size_t)v * NFEAT + fo);
    float4 bv = *(const float4*)(bias + fo);
    acc.x += nm * hv.x + bv.x;
    acc.y += nm * hv.y + bv.y;
    acc.z += nm * hv.z + bv.z;
    acc.w += nm * hv.w + bv.w;
    if (do_relu) {
        acc.x = fmaxf(acc.x, 0.f);
        acc.y = fmaxf(acc.y, 0.f);
        acc.z = fmaxf(acc.z, 0.f);
        acc.w = fmaxf(acc.w, 0.f);
    }
    *(float4*)(out + (size_t)v * NFEAT + fo) = acc;
}

// ---------------- pooling (batch sorted -> boundary detect, no atomics) ----------------

__global__ void bounds_kernel(const void* __restrict__ batch, const int* __restrict__ flag,
                              int* __restrict__ gstart, int* __restrict__ gend, int n) {
    int is64 = *flag;
    int i = blockIdx.x * blockDim.x + threadIdx.x;
    if (i >= n) return;
    int g = load_idx(batch, i, is64);
    if (i == 0) {
        gstart[g] = 0;
    } else {
        int gp = load_idx(batch, i - 1, is64);
        if (gp != g) {
            gend[gp]  = i;
            gstart[g] = i;
        }
    }
    if (i == n - 1) gend[g] = n;
}

__global__ void pool_kernel(const float* __restrict__ B, const int* __restrict__ gstart,
                            const int* __restrict__ gend, float* __restrict__ psum) {
    int g    = blockIdx.x / POOL_SPLIT;
    int part = blockIdx.x % POOL_SPLIT;
    int c    = threadIdx.x;
    int s = gstart[g], e = gend[g];
    if (s > e) { s = 0; e = 0; }
    int len   = e - s;
    int chunk = (len + POOL_SPLIT - 1) / POOL_SPLIT;
    int ls = s + part * chunk;
    int le = min(ls + chunk, e);
    float acc = 0.f;
    for (int i = ls; i < le; i++) acc += B[(size_t)i * NFEAT + c];
    psum[((size_t)g * POOL_SPLIT + part) * NFEAT + c] = acc;
}

__global__ void pool_reduce_kernel(const float* __restrict__ psum, const int* __restrict__ gstart,
                                   const int* __restrict__ gend, float* __restrict__ pooled) {
    int g = blockIdx.x;
    int c = threadIdx.x;
    float acc = 0.f;
#pragma unroll
    for (int p = 0; p < POOL_SPLIT; p++)
        acc += psum[((size_t)g * POOL_SPLIT + p) * NFEAT + c];
    int cn = gend[g] - gstart[g];
    float denom = (cn > 0) ? (float)cn : 1.0f;
    pooled[g * NFEAT + c] = acc / denom;
}

__global__ void final_kernel(const float* __restrict__ pooled, const float* __restrict__ lw,
                             const float* __restrict__ lb, float* __restrict__ out) {
    int idx = blockIdx.x * blockDim.x + threadIdx.x;
    if (idx >= NGRAPH * 16) return;
    int g = idx >> 4, c = idx & 15;
    float acc = lb[c];
#pragma unroll 8
    for (int k = 0; k < 128; k++) acc += pooled[g * NFEAT + k] * lw[k * 16 + c];
    out[idx] = acc;
}

// ---------------- launch ----------------

extern "C" void kernel_launch(void* const* d_in, const int* in_sizes, int n_in,
                              void* d_out, int out_size, void* d_ws, size_t ws_size,
                              hipStream_t stream) {
    const float* x   = (const float*)d_in[0];
    const void*  ei  = d_in[1];
    const void*  bat = d_in[2];
    const float* W1  = (const float*)d_in[3];
    const float* b1  = (const float*)d_in[4];
    const float* W2  = (const float*)d_in[5];
    const float* b2  = (const float*)d_in[6];
    const float* W3  = (const float*)d_in[7];
    const float* b3  = (const float*)d_in[8];
    const float* lw  = (const float*)d_in[9];
    const float* lb  = (const float*)d_in[10];
    float*       out = (float*)d_out;

    const int n  = in_sizes[0] / NFEAT;  // 50000
    const int nE = in_sizes[1] / 2;      // 800000

    char* ws = (char*)d_ws;
    size_t off = 0;
    auto alloc = [&](size_t bytes) -> char* {
        char* p = ws + off;
        off = (off + bytes + 255) & ~(size_t)255;
        return p;
    };
    int*    flag      = (int*)alloc(256);
    int*    cnt       = (int*)alloc((size_t)n * 4);
    int*    row_start = (int*)alloc((size_t)(n + 1) * 4);
    int*    cursor    = (int*)alloc((size_t)n * 4);
    int*    bsum      = (int*)alloc(1024);
    float2* csr       = (float2*)alloc((size_t)nE * 8);
    float*  dinv      = (float*)alloc((size_t)n * 4);
    int*    gstart    = (int*)alloc(NGRAPH * 4);
    int*    gend      = (int*)alloc(NGRAPH * 4);
    float*  psum      = (float*)alloc((size_t)NGRAPH * POOL_SPLIT * NFEAT * 4);
    float*  pooled    = (float*)alloc(NGRAPH * NFEAT * 4);
    float*  bufA      = (float*)alloc((size_t)n * NFEAT * 4);
    float*  bufB      = (float*)alloc((size_t)n * NFEAT * 4);
    (void)ws_size;

    const int TB  = 256;
    const int nbE = (nE + TB - 1) / TB;
    const int nbN = (n + TB - 1) / TB;

    hipMemsetAsync(cnt, 0, (size_t)n * 4, stream);
    hipMemsetAsync(cursor, 0, (size_t)n * 4, stream);
    hipMemsetAsync(gstart, 0x7f, NGRAPH * 4, stream);
    hipMemsetAsync(gend, 0, NGRAPH * 4, stream);

    detect_kernel<<<1, 256, 0, stream>>>((const unsigned int*)ei, flag);
    deg_kernel<<<nbE, TB, 0, stream>>>(ei, flag, cnt, nE);
    scanA<<<nbN, 256, 0, stream>>>(cnt, row_start, bsum, dinv, n);
    scanB<<<1, 256, 0, stream>>>(bsum, nbN, row_start + n);
    scanC<<<nbN, 256, 0, stream>>>(row_start, bsum, n);
    fill_kernel<<<nbE, TB, 0, stream>>>(ei, flag, row_start, cursor, dinv, csr, nE);

    const int gemmBlocks = (n + GR - 1) / GR;
    const int aggBlocks  = (n + 7) / 8;

    gemm_kernel<<<gemmBlocks, 256, 0, stream>>>(x, W1, bufA, n);
    agg_kernel<<<aggBlocks, 256, 0, stream>>>(bufA, row_start, csr, dinv, b1, bufB, n, 1);
    gemm_kernel<<<gemmBlocks, 256, 0, stream>>>(bufB, W2, bufA, n);
    agg_kernel<<<aggBlocks, 256, 0, stream>>>(bufA, row_start, csr, dinv, b2, bufB, n, 1);
    gemm_kernel<<<gemmBlocks, 256, 0, stream>>>(bufB, W3, bufA, n);
    agg_kernel<<<aggBlocks, 256, 0, stream>>>(bufA, row_start, csr, dinv, b3, bufB, n, 0);

    bounds_kernel<<<nbN, TB, 0, stream>>>(bat, flag, gstart, gend, n);
    pool_kernel<<<NGRAPH * POOL_SPLIT, NFEAT, 0, stream>>>(bufB, gstart, gend, psum);
    pool_reduce_kernel<<<NGRAPH, NFEAT, 0, stream>>>(psum, gstart, gend, pooled);
    final_kernel<<<(NGRAPH * 16 + 255) / 256, 256, 0, stream>>>(pooled, lw, lb, out);
}